// Round 13
// baseline (167.946 us; speedup 1.0000x reference)
//
#include <hip/hip_runtime.h>
#include <cstdint>
#include <cstddef>

// Problem constants (B, S, E, H, MAXLEN) = (2, 2048, 1024, 16, 2048)
constexpr int Sn = 2048;
constexpr int En = 1024;
constexpr int Bn = 2;
constexpr int Hn = 16;
constexpr int CHUNK = 32;          // 32-row chunks (2 per wave tile)
constexpr int NCH = Sn / CHUNK;    // 64 chunks per batch
constexpr int Mtot = Bn * Sn;      // 4096
constexpr int GCH = Mtot / CHUNK;  // 128 global chunks

typedef __bf16 bf16x8 __attribute__((ext_vector_type(8)));
typedef float  f32x4  __attribute__((ext_vector_type(4)));

__device__ __forceinline__ unsigned short f2bf(float f) {
    union { float f; uint32_t u; } v; v.f = f;
    const uint32_t u = v.u;
    return (unsigned short)((u + 0x7fffu + ((u >> 16) & 1u)) >> 16);  // RNE
}
__device__ __forceinline__ float bf2f(unsigned short s) {
    union { uint32_t u; float f; } v; v.u = (uint32_t)s << 16; return v.f;
}

// ---------------------------------------------------------------------------
// Fused fp32 -> bf16 cast of x (XN) and Wv (WN) in one launch.
// [R15: in-GEMM fp32 staging +16 µs. R7: coop fusion +200 µs. R11: split-K
// +7 µs. R12 algebra: inter-dispatch gaps ~0-2 µs (graph-captured).]
// ---------------------------------------------------------------------------
constexpr int XN = Bn * Sn * En;   // 4194304
constexpr int WN = En * En;        // 1048576

__global__ __launch_bounds__(256)
void cast2(const float* __restrict__ x, const float* __restrict__ Wv,
           unsigned short* __restrict__ xb, unsigned short* __restrict__ Wvb)
{
    const int i = (blockIdx.x * 256 + threadIdx.x) * 4;
    const float* src; unsigned short* dst; int off;
    if (i < XN) { src = x;  dst = xb;  off = i; }
    else        { src = Wv; dst = Wvb; off = i - XN; }
    const float4 v = *(const float4*)(src + off);
    ushort4 o;
    o.x = f2bf(v.x); o.y = f2bf(v.y); o.z = f2bf(v.z); o.w = f2bf(v.w);
    *(ushort4*)(dst + off) = o;
}

// ---------------------------------------------------------------------------
// bf16 MFMA GEMM (NT) — R8 configuration (session best: 163.06 µs total).
// C[m,n] = sum_k A[m,k]*W[n,k] + bias[n].
// Tile 128(M) x 64(N), BK=64, 256 threads = 4 waves in 2x2, wave tile 64x32.
// LDS double-buffer: step t reads buf[t&1], stores tile t+1 AFTER compute.
// [PLATEAU NOTE — 15 structural variants across 2 sessions all land at
// 34-40 µs/GEMM at this shape (M=4096,N=1024,K=1024 ~ 253 TF, on m102's
// shape curve): prefetch depth, staged dtype, tile 64²/128x64/128², glds
// vs reg-stage, flatmm, BK 32/64/128, barrier count, light-vs-heavy
// barriers, no-LDS direct, split-K, coop fusion, 4-blk occupancy.
// Counters at plateau: MfmaUtil ~6%, VALUBusy ~7%, HBM ~8%, 0 bank
// conflicts — latency-bound small-shape regime; per-CU time invariant to
// phase count and per-phase work (R3==R6). Do not re-enter.]
// ---------------------------------------------------------------------------
#define LOAD6(k0, r0, r1, r2, r3, r4, r5)            \
    r0 = *(const uint4*)(gA0 + (k0));                \
    r1 = *(const uint4*)(gA0 + (k0) + 32);           \
    r2 = *(const uint4*)(gA1 + (k0));                \
    r3 = *(const uint4*)(gA1 + (k0) + 32);           \
    r4 = *(const uint4*)(gB0 + (k0));                \
    r5 = *(const uint4*)(gB0 + (k0) + 32);

#define STORE6B(B, r0, r1, r2, r3, r4, r5)                       \
    *(uint4*)&As[B][(rg0 * 2 + 0) * 512 + lane * 8] = r0;        \
    *(uint4*)&As[B][(rg0 * 2 + 1) * 512 + lane * 8] = r1;        \
    *(uint4*)&As[B][(rg1 * 2 + 0) * 512 + lane * 8] = r2;        \
    *(uint4*)&As[B][(rg1 * 2 + 1) * 512 + lane * 8] = r3;        \
    *(uint4*)&Bs[B][(wv  * 2 + 0) * 512 + lane * 8] = r4;        \
    *(uint4*)&Bs[B][(wv  * 2 + 1) * 512 + lane * 8] = r5;

#define COMPUTEB(B)                                                                            \
    {                                                                                          \
        bf16x8 af[4][2], bfr[2][2];                                                            \
        _Pragma("unroll")                                                                      \
        for (int i = 0; i < 4; ++i)                                                            \
            _Pragma("unroll")                                                                  \
            for (int kh = 0; kh < 2; ++kh)                                                     \
                af[i][kh] = *(const bf16x8*)&As[B][((wr * 4 + i) * 2 + kh) * 512 + lane * 8];   \
        _Pragma("unroll")                                                                      \
        for (int j = 0; j < 2; ++j)                                                            \
            _Pragma("unroll")                                                                  \
            for (int kh = 0; kh < 2; ++kh)                                                     \
                bfr[j][kh] = *(const bf16x8*)&Bs[B][((wc * 2 + j) * 2 + kh) * 512 + lane * 8]; \
        _Pragma("unroll")                                                                      \
        for (int kh = 0; kh < 2; ++kh)                                                         \
            _Pragma("unroll")                                                                  \
            for (int i = 0; i < 4; ++i)                                                        \
                _Pragma("unroll")                                                              \
                for (int j = 0; j < 2; ++j)                                                    \
                    acc[i][j] = __builtin_amdgcn_mfma_f32_16x16x32_bf16(af[i][kh], bfr[j][kh], \
                                                                        acc[i][j], 0, 0, 0);   \
    }

template<bool APPLY_MASK, bool OUT_BF16, bool FUSE_CSUM>
__global__ __launch_bounds__(256)
void gemm_pipe(const unsigned short* __restrict__ A, const unsigned short* __restrict__ Bw,
               const float* __restrict__ bias, const int* __restrict__ mask,
               void* __restrict__ Cv, float* __restrict__ csum)
{
    __shared__ __align__(16) unsigned short As[2][128 * 64];  // 2 x 16 KB
    __shared__ __align__(16) unsigned short Bs[2][64 * 64];   // 2 x 8 KB

    const int tid  = threadIdx.x;
    const int lane = tid & 63;
    const int wv   = tid >> 6;      // wave 0..3
    const int wr   = wv >> 1;       // wave row (0..1) -> M
    const int wc   = wv & 1;        // wave col (0..1) -> N
    // XCD-aware swizzle (grid (16, 32)).
    const int id   = blockIdx.y * 16 + blockIdx.x;
    const int xcd  = id & 7;
    const int slot = id >> 3;
    const int by   = xcd * 4 + (slot >> 4);
    const int bx   = slot & 15;
    const int bm   = by * 128;
    const int bn   = bx * 64;
    const int m16  = lane & 15;
    const int kq   = lane >> 4;     // k-quarter (staging) / row-quad (C/D)

    f32x4 acc[4][2] = {};

    const int rg0 = 2 * wv, rg1 = 2 * wv + 1;
    const unsigned short* gA0 = A  + (size_t)(bm + 16 * rg0 + m16) * En + kq * 8;
    const unsigned short* gA1 = A  + (size_t)(bm + 16 * rg1 + m16) * En + kq * 8;
    const unsigned short* gB0 = Bw + (size_t)(bn + 16 * wv  + m16) * En + kq * 8;

    // 12 individually named staging registers (arrays spill — R6 lesson).
    uint4 p0, p1, p2, p3, p4, p5;
    uint4 q0, q1, q2, q3, q4, q5;

    // Pipeline: step t reads buf[t&1]; stores for tile t+1 happen at step t
    // AFTER compute. K=1024, BK=64 -> 16 K-steps.
    LOAD6(0,  p0, p1, p2, p3, p4, p5);          // tile 0
    STORE6B(0, p0, p1, p2, p3, p4, p5);         // waits vmcnt(0) once
    LOAD6(64, q0, q1, q2, q3, q4, q5);          // tile 1
    __syncthreads();                            // buf0 ready

#pragma unroll 1
    for (int it = 0; it < 7; ++it) {            // steps 0..13
        const int kb = it * 128;
        // even step 2it: read buf0
        LOAD6(kb + 128, p0, p1, p2, p3, p4, p5);     // tile 2it+2
        COMPUTEB(0);
        STORE6B(1, q0, q1, q2, q3, q4, q5);          // tile 2it+1
        __syncthreads();
        // odd step 2it+1: read buf1
        LOAD6(kb + 192, q0, q1, q2, q3, q4, q5);     // tile 2it+3
        COMPUTEB(1);
        STORE6B(0, p0, p1, p2, p3, p4, p5);          // tile 2it+2
        __syncthreads();
    }
    // step 14: read buf0 (tile 14); stage tile 15
    COMPUTEB(0);
    STORE6B(1, q0, q1, q2, q3, q4, q5);
    __syncthreads();
    // step 15: read buf1 (tile 15)
    COMPUTEB(1);

    // Epilogue. C/D layout: col = lane&15, row = (lane>>4)*4 + reg.
    float colsum[2][2] = {{0.0f, 0.0f}, {0.0f, 0.0f}};
#pragma unroll
    for (int i = 0; i < 4; ++i) {
        const int r0_ = bm + wr * 64 + i * 16 + kq * 4;
#pragma unroll
        for (int j = 0; j < 2; ++j) {
            const int c0 = bn + wc * 32 + j * 16 + m16;
            const float bcol = bias[c0];
#pragma unroll
            for (int r = 0; r < 4; ++r) {
                const int row = r0_ + r;
                float val = acc[i][j][r] + bcol;
                if (APPLY_MASK) val = (mask[row] == 0) ? 0.0f : val;
                if (FUSE_CSUM) colsum[i >> 1][j] += val;
                if (OUT_BF16)
                    ((unsigned short*)Cv)[(size_t)row * En + c0] = f2bf(val);
                else
                    ((float*)Cv)[(size_t)row * En + c0] = val;
            }
        }
    }

    if (FUSE_CSUM) {
        // Wave wr's 64 rows = global chunks {4*by + 2*wr, +1} (CHUNK=32).
        const int gc0 = 4 * by + 2 * wr;
#pragma unroll
        for (int g = 0; g < 2; ++g)
#pragma unroll
            for (int j = 0; j < 2; ++j) {
                float s = colsum[g][j];
                s += __shfl_xor(s, 16, 64);
                s += __shfl_xor(s, 32, 64);
                if (kq == 0)
                    csum[(size_t)(gc0 + g) * En + bn + wc * 32 + j * 16 + m16] = s;
            }
    }
}

// ---------------------------------------------------------------------------
// prescan (R26): exclusive chunk-prefix per (b,e) column, computed ONCE.
// [Previously every one of 512 combine blocks re-scanned all 64 chunk sums
// (64 strided L2 loads + serial adds, 64x redundant). 8 blocks x 256 thr =
// 2048 threads = one per column. ~2-3 µs; gap cost ~0 (R12 algebra).]
// ---------------------------------------------------------------------------
__global__ __launch_bounds__(256)
void prescan(const float* __restrict__ csum, float* __restrict__ pref,
             float* __restrict__ Tbuf)
{
    const int e = blockIdx.x * 256 + threadIdx.x;   // 0..1023
    const int b = blockIdx.y;                       // 0..1
    const float* cp = csum + (size_t)b * NCH * En + e;
    float*       pp = pref + (size_t)b * NCH * En + e;
    float run = 0.0f;
#pragma unroll 8
    for (int c2 = 0; c2 < NCH; ++c2) {
        pp[(size_t)c2 * En] = run;
        run += cp[(size_t)c2 * En];
    }
    Tbuf[b * En + e] = run;
}

// ---------------------------------------------------------------------------
// combine (R26): Wo cast slice + LDS-staged vm tile + weighted combine.
// Scan replaced by 2 loads (pref, Tbuf) from prescan.
//   out_pre[b,i,e] = (w2*Pref[i&~1] + (i odd)*w1*vm[i-1] + w0*(T-Pref[i]))/Z
//   Z = (i&~1)*w2 + (i odd)*w1 + (S-i)*w0 + 1e-8
// Grid (4, 64, 2) = 512 blocks = 2/CU. Chunk starts even, so odd-i prev is
// always in-chunk. gemm2 (reads Wob) launches after us.
// ---------------------------------------------------------------------------
__global__ __launch_bounds__(256)
void combine(const unsigned short* __restrict__ vm, const float* __restrict__ pref,
             const float* __restrict__ Tbuf,
             const float* __restrict__ hier, const float* __restrict__ Wo,
             unsigned short* __restrict__ Wob, unsigned short* __restrict__ opre)
{
    __shared__ __align__(16) unsigned short tile[CHUNK * 256];  // 16 KB

    const int tid = threadIdx.x;
    const int ec0 = blockIdx.x * 256;
    const int c   = blockIdx.y;     // chunk within batch, 0..63
    const int b   = blockIdx.z;

    // --- Stage 32x256 vm tile -> LDS: 4 passes x (8 rows x 32 lanes x 16 B).
    {
        const int lane16 = tid & 31;          // 16B segment within a row
        const int rbase  = tid >> 5;          // 0..7
        const size_t g0 = ((size_t)b * Sn + c * CHUNK) * En + ec0 + lane16 * 8;
#pragma unroll
        for (int r4 = 0; r4 < 4; ++r4) {
            const int row = r4 * 8 + rbase;
            *(uint4*)&tile[row * 256 + lane16 * 8] =
                *(const uint4*)(vm + g0 + (size_t)row * En);
        }
    }

    // --- Wo cast slice: 512 blocks x 256 threads x 8 elems = 1M elements.
    {
        const int fid = (blockIdx.z * 64 + blockIdx.y) * 4 + blockIdx.x;  // 0..511
        const int base = fid * 2048 + tid * 4;
#pragma unroll
        for (int half = 0; half < 2; ++half) {
            const int off = base + half * 1024;
            const float4 v = *(const float4*)(Wo + off);
            ushort4 o;
            o.x = f2bf(v.x); o.y = f2bf(v.y); o.z = f2bf(v.z); o.w = f2bf(v.w);
            *(ushort4*)(Wob + off) = o;
        }
    }

    const int e = ec0 + tid;
    const int h = e >> 6;   // dh = 64
    const float w0 = hier[((size_t)b * Hn + h) * 3 + 0];
    const float w1 = hier[((size_t)b * Hn + h) * 3 + 1] * 0.5f;
    const float w2 = hier[((size_t)b * Hn + h) * 3 + 2] * 0.25f;

    // --- Prefix and total from prescan (2 loads; scan loop eliminated).
    float run = pref[(size_t)(b * NCH + c) * En + e];
    const float T = Tbuf[b * En + e];

    __syncthreads();   // vm tile visible

    float prev = 0.0f;
    const size_t base = ((size_t)b * Sn + c * CHUNK) * En + e;

#pragma unroll
    for (int t = 0; t < CHUNK; ++t) {
        const int i = c * CHUNK + t;
        const float cur = bf2f(tile[t * 256 + tid]);
        float num, Z;
        if (i & 1) {
            num = w2 * (run - prev) + w1 * prev + w0 * (T - run);
            Z = (float)(i - 1) * w2 + w1 + (float)(Sn - i) * w0 + 1e-8f;
        } else {
            num = w2 * run + w0 * (T - run);
            Z = (float)i * w2 + (float)(Sn - i) * w0 + 1e-8f;
        }
        opre[base + (size_t)t * En] = f2bf(num / Z);
        run += cur;
        prev = cur;
    }
}

// ---------------------------------------------------------------------------
extern "C" void kernel_launch(void* const* d_in, const int* in_sizes, int n_in,
                              void* d_out, int out_size, void* d_ws, size_t ws_size,
                              hipStream_t stream)
{
    // 0:x 1:attention_mask 2:level_indices 3:Wq 4:bq 5:Wk 6:bk 7:Wv 8:bv 9:hier 10:Wo 11:bo
    const float* x    = (const float*)d_in[0];
    const int*   mask = (const int*)d_in[1];
    const float* Wv   = (const float*)d_in[7];
    const float* bv   = (const float*)d_in[8];
    const float* hier = (const float*)d_in[9];
    const float* Wo   = (const float*)d_in[10];
    const float* bo   = (const float*)d_in[11];
    float* out = (float*)d_out;

    char* ws = (char*)d_ws;
    unsigned short* xb    = (unsigned short*)ws;  ws += (size_t)Mtot * En * 2;   // 8 MB
    unsigned short* Wvb   = (unsigned short*)ws;  ws += (size_t)En * En * 2;     // 2 MB
    unsigned short* Wob   = (unsigned short*)ws;  ws += (size_t)En * En * 2;     // 2 MB
    unsigned short* vmb   = (unsigned short*)ws;  ws += (size_t)Mtot * En * 2;   // 8 MB
    float*          csum  = (float*)ws;           ws += (size_t)GCH * En * 4;    // 512 KB
    float*          pref  = (float*)ws;           ws += (size_t)GCH * En * 4;    // 512 KB
    float*          Tbuf  = (float*)ws;           ws += (size_t)Bn * En * 4;     // 8 KB
    unsigned short* opreb = (unsigned short*)ws;  ws += (size_t)Mtot * En * 2;   // 8 MB

    dim3 threads(256);

    // Casts to bf16: x + Wv only (Wo is cast inside combine, pre-gemm2)
    cast2<<<dim3((XN + WN) / 1024), threads, 0, stream>>>(x, Wv, xb, Wvb);

    dim3 gemm_grid(16, 32);   // 512 blocks = 2/CU (XCD-swizzled in-kernel)

    // 1) vm = mask ? (x @ Wv.T + bv) : 0 (bf16) + fused 32-row chunk col sums
    gemm_pipe<true, true, true><<<gemm_grid, threads, 0, stream>>>(xb, Wvb, bv, mask, vmb, csum);
    // 2) exclusive chunk-prefix per column, once (was 64x-redundant in combine)
    prescan<<<dim3(4, 2), threads, 0, stream>>>(csum, pref, Tbuf);
    // 3) Wo cast + LDS-staged weighted combine -> opre (bf16)
    combine<<<dim3(En / 256, NCH, Bn), threads, 0, stream>>>(vmb, pref, Tbuf, hier, Wo, Wob, opreb);
    // 4) out = opre @ Wo.T + bo (fp32 out)
    gemm_pipe<false, false, false><<<gemm_grid, threads, 0, stream>>>(opreb, Wob, bo, nullptr, out, nullptr);
}

// Round 14
// 162.449 us; speedup vs baseline: 1.0338x; 1.0338x over previous
//
#include <hip/hip_runtime.h>
#include <cstdint>
#include <cstddef>

// Problem constants (B, S, E, H, MAXLEN) = (2, 2048, 1024, 16, 2048)
constexpr int Sn = 2048;
constexpr int En = 1024;
constexpr int Bn = 2;
constexpr int Hn = 16;
constexpr int CHUNK = 32;          // 32-row chunks (2 per wave tile)
constexpr int NCH = Sn / CHUNK;    // 64 chunks per batch
constexpr int Mtot = Bn * Sn;      // 4096
constexpr int GCH = Mtot / CHUNK;  // 128 global chunks

typedef __bf16 bf16x8 __attribute__((ext_vector_type(8)));
typedef float  f32x4  __attribute__((ext_vector_type(4)));

__device__ __forceinline__ unsigned short f2bf(float f) {
    union { float f; uint32_t u; } v; v.f = f;
    const uint32_t u = v.u;
    return (unsigned short)((u + 0x7fffu + ((u >> 16) & 1u)) >> 16);  // RNE
}
__device__ __forceinline__ float bf2f(unsigned short s) {
    union { uint32_t u; float f; } v; v.u = (uint32_t)s << 16; return v.f;
}

// ---------------------------------------------------------------------------
// Fused fp32 -> bf16 cast of x (XN) and Wv (WN) in one launch.
// [R15: in-GEMM fp32 staging +16 µs. R7: coop fusion +200 µs. R13: extra
// prescan dispatch +4.8 µs (scan was latency-hidden in combine).]
// ---------------------------------------------------------------------------
constexpr int XN = Bn * Sn * En;   // 4194304
constexpr int WN = En * En;        // 1048576

__global__ __launch_bounds__(256)
void cast2(const float* __restrict__ x, const float* __restrict__ Wv,
           unsigned short* __restrict__ xb, unsigned short* __restrict__ Wvb)
{
    const int i = (blockIdx.x * 256 + threadIdx.x) * 4;
    const float* src; unsigned short* dst; int off;
    if (i < XN) { src = x;  dst = xb;  off = i; }
    else        { src = Wv; dst = Wvb; off = i - XN; }
    const float4 v = *(const float4*)(src + off);
    ushort4 o;
    o.x = f2bf(v.x); o.y = f2bf(v.y); o.z = f2bf(v.z); o.w = f2bf(v.w);
    *(ushort4*)(dst + off) = o;
}

// ---------------------------------------------------------------------------
// Traffic model (R14): GEMM time tracks aggregate L2/L3 READ bytes at
// ~6-7 TB/s (R3/R8:192MB->32µs; R2:384->56; R9:392->58; R5:+33%->+20%),
// provided >=2 blocks/CU co-reside (R6: 128MB but 1 blk/CU -> latency-bound
// at same 32µs). FETCH_SIZE misses this (HBM-only; L3 serves the re-reads).
// At this shape the only config with BOTH lower traffic AND 2 blocks/CU is
// a 128x128 tile with split-K=2 (512 blocks, A re-read 16x->8x: 192->128MB).
// ---------------------------------------------------------------------------

// --- Shared macros: verified R8 chunk layout (16 rows x 32 k, lane*16B). ---
#define LOAD8(k0, a0, a1, a2, a3, b0, b1, b2, b3)    \
    a0 = *(const uint4*)(gA0 + (k0));                \
    a1 = *(const uint4*)(gA0 + (k0) + 32);           \
    a2 = *(const uint4*)(gA1 + (k0));                \
    a3 = *(const uint4*)(gA1 + (k0) + 32);           \
    b0 = *(const uint4*)(gB0 + (k0));                \
    b1 = *(const uint4*)(gB0 + (k0) + 32);           \
    b2 = *(const uint4*)(gB1 + (k0));                \
    b3 = *(const uint4*)(gB1 + (k0) + 32);

#define STORE8B(B, a0, a1, a2, a3, b0, b1, b2, b3)               \
    *(uint4*)&As[B][(rg0 * 2 + 0) * 512 + lane * 8] = a0;        \
    *(uint4*)&As[B][(rg0 * 2 + 1) * 512 + lane * 8] = a1;        \
    *(uint4*)&As[B][(rg1 * 2 + 0) * 512 + lane * 8] = a2;        \
    *(uint4*)&As[B][(rg1 * 2 + 1) * 512 + lane * 8] = a3;        \
    *(uint4*)&Bs[B][(rg0 * 2 + 0) * 512 + lane * 8] = b0;        \
    *(uint4*)&Bs[B][(rg0 * 2 + 1) * 512 + lane * 8] = b1;        \
    *(uint4*)&Bs[B][(rg1 * 2 + 0) * 512 + lane * 8] = b2;        \
    *(uint4*)&Bs[B][(rg1 * 2 + 1) * 512 + lane * 8] = b3;

#define COMPUTE44(B)                                                                           \
    {                                                                                          \
        bf16x8 af[4][2], bfr[4][2];                                                            \
        _Pragma("unroll")                                                                      \
        for (int i = 0; i < 4; ++i)                                                            \
            _Pragma("unroll")                                                                  \
            for (int kh = 0; kh < 2; ++kh)                                                     \
                af[i][kh] = *(const bf16x8*)&As[B][((wr * 4 + i) * 2 + kh) * 512 + lane * 8];   \
        _Pragma("unroll")                                                                      \
        for (int j = 0; j < 4; ++j)                                                            \
            _Pragma("unroll")                                                                  \
            for (int kh = 0; kh < 2; ++kh)                                                     \
                bfr[j][kh] = *(const bf16x8*)&Bs[B][((wc * 4 + j) * 2 + kh) * 512 + lane * 8]; \
        _Pragma("unroll")                                                                      \
        for (int kh = 0; kh < 2; ++kh)                                                         \
            _Pragma("unroll")                                                                  \
            for (int i = 0; i < 4; ++i)                                                        \
                _Pragma("unroll")                                                              \
                for (int j = 0; j < 4; ++j)                                                    \
                    acc[i][j] = __builtin_amdgcn_mfma_f32_16x16x32_bf16(af[i][kh], bfr[j][kh], \
                                                                        acc[i][j], 0, 0, 0);   \
    }

// ---------------------------------------------------------------------------
// gemm1_sk128 — 128x128 tile, 4 waves (2x2, wave tile 64x64), split-K=2.
// Grid (8,32,2) = 512 blocks = 2/CU. LDS 2 x 32 KB dbuf. 8 K-steps/block.
// Traffic: A 8MB x 8 + B 2MB x 32 = 128 MB (was 192). Per-step staging and
// fragment math verbatim from R8/R11 verified code (B rows doubled).
// Reduction folds into combine (mask & bias linear): vm0/vm1 bf16 partials
// + csum0/csum1; bias added in half ks==0 only; mask applied both halves.
// ---------------------------------------------------------------------------
__global__ __launch_bounds__(256, 2)
void gemm1_sk128(const unsigned short* __restrict__ A, const unsigned short* __restrict__ Bw,
                 const float* __restrict__ bias, const int* __restrict__ mask,
                 unsigned short* __restrict__ vm0, unsigned short* __restrict__ vm1,
                 float* __restrict__ csum0, float* __restrict__ csum1)
{
    __shared__ __align__(16) unsigned short As[2][128 * 64];  // 2 x 16 KB
    __shared__ __align__(16) unsigned short Bs[2][128 * 64];  // 2 x 16 KB

    const int tid  = threadIdx.x;
    const int lane = tid & 63;
    const int wv   = tid >> 6;      // wave 0..3
    const int wr   = wv >> 1;       // wave row (0..1) -> 64-row half
    const int wc   = wv & 1;        // wave col (0..1) -> 64-col half
    // XCD-aware swizzle (256 blocks per K-half; bijective, R6 pattern).
    const int id   = blockIdx.y * 8 + blockIdx.x;   // 0..255
    const int xcd  = id & 7;
    const int slot = id >> 3;       // 0..31
    const int by   = xcd * 4 + (slot >> 3);   // 0..31
    const int bx   = slot & 7;                // 0..7
    const int bm   = by * 128;
    const int bn   = bx * 128;
    const int m16  = lane & 15;
    const int kq   = lane >> 4;     // k-quarter (staging) / row-quad (C/D)
    const int ks   = blockIdx.z;    // K-half 0/1

    f32x4 acc[4][4] = {};

    const int rg0 = 2 * wv, rg1 = 2 * wv + 1;     // row-groups 0..7
    const size_t koff = (size_t)ks * 512;
    const unsigned short* gA0 = A  + (size_t)(bm + 16 * rg0 + m16) * En + koff + kq * 8;
    const unsigned short* gA1 = A  + (size_t)(bm + 16 * rg1 + m16) * En + koff + kq * 8;
    const unsigned short* gB0 = Bw + (size_t)(bn + 16 * rg0 + m16) * En + koff + kq * 8;
    const unsigned short* gB1 = Bw + (size_t)(bn + 16 * rg1 + m16) * En + koff + kq * 8;

    // 16 individually named staging registers (arrays spill — R6 lesson).
    uint4 p0, p1, p2, p3, p4, p5, p6, p7;
    uint4 q0, q1, q2, q3, q4, q5, q6, q7;

    // K=512 per half, BK=64 -> 8 K-steps. Verified dbuf pipeline (R8/R11).
    LOAD8(0,  p0, p1, p2, p3, p4, p5, p6, p7);      // tile 0
    STORE8B(0, p0, p1, p2, p3, p4, p5, p6, p7);
    LOAD8(64, q0, q1, q2, q3, q4, q5, q6, q7);      // tile 1
    __syncthreads();

#pragma unroll 1
    for (int it = 0; it < 3; ++it) {                // steps 0..5
        const int kb = it * 128;
        LOAD8(kb + 128, p0, p1, p2, p3, p4, p5, p6, p7);   // tile 2it+2
        COMPUTE44(0);
        STORE8B(1, q0, q1, q2, q3, q4, q5, q6, q7);
        __syncthreads();
        LOAD8(kb + 192, q0, q1, q2, q3, q4, q5, q6, q7);   // tile 2it+3 (<=7)
        COMPUTE44(1);
        STORE8B(0, p0, p1, p2, p3, p4, p5, p6, p7);
        __syncthreads();
    }
    // step 6: tile 6 in buf0; stage tile 7
    COMPUTE44(0);
    STORE8B(1, q0, q1, q2, q3, q4, q5, q6, q7);
    __syncthreads();
    // step 7: tile 7
    COMPUTE44(1);

    // Epilogue. C/D layout: col = lane&15, row = (lane>>4)*4 + reg.
    unsigned short* vmk = ks ? vm1 : vm0;
    float*          csk = ks ? csum1 : csum0;
    float colsum[2][4] = {};
#pragma unroll
    for (int i = 0; i < 4; ++i) {
        const int r0_ = bm + wr * 64 + i * 16 + kq * 4;
#pragma unroll
        for (int j = 0; j < 4; ++j) {
            const int c0 = bn + wc * 64 + j * 16 + m16;
            const float bcol = (ks == 0) ? bias[c0] : 0.0f;
#pragma unroll
            for (int r = 0; r < 4; ++r) {
                const int row = r0_ + r;
                float val = acc[i][j][r] + bcol;
                val = (mask[row] == 0) ? 0.0f : val;   // mask linear over halves
                colsum[i >> 1][j] += val;
                vmk[(size_t)row * En + c0] = f2bf(val);
            }
        }
    }
    {
        // Wave wr's 64 rows = global chunks {4*by + 2*wr, +1} (CHUNK=32).
        const int gc0 = 4 * by + 2 * wr;
#pragma unroll
        for (int g = 0; g < 2; ++g)
#pragma unroll
            for (int j = 0; j < 4; ++j) {
                float s = colsum[g][j];
                s += __shfl_xor(s, 16, 64);
                s += __shfl_xor(s, 32, 64);
                if (kq == 0)
                    csk[(size_t)(gc0 + g) * En + bn + wc * 64 + j * 16 + m16] = s;
            }
    }
}

// ---------------------------------------------------------------------------
// gemm2 — R8 configuration verbatim (128x64, 4 waves, dbuf, 16 K-steps).
// [PLATEAU NOTE: 15 structural variants all 34-40 µs at this shape; do not
// re-enter without a traffic reduction + 2 blocks/CU (see model above).
// gemm2 has no cheap reduction sink for split-K (fp32 out), left as-is.]
// ---------------------------------------------------------------------------
#define LOAD6(k0, r0, r1, r2, r3, r4, r5)            \
    r0 = *(const uint4*)(gA0 + (k0));                \
    r1 = *(const uint4*)(gA0 + (k0) + 32);           \
    r2 = *(const uint4*)(gA1 + (k0));                \
    r3 = *(const uint4*)(gA1 + (k0) + 32);           \
    r4 = *(const uint4*)(gB0 + (k0));                \
    r5 = *(const uint4*)(gB0 + (k0) + 32);

#define STORE6B(B, r0, r1, r2, r3, r4, r5)                       \
    *(uint4*)&As[B][(rg0 * 2 + 0) * 512 + lane * 8] = r0;        \
    *(uint4*)&As[B][(rg0 * 2 + 1) * 512 + lane * 8] = r1;        \
    *(uint4*)&As[B][(rg1 * 2 + 0) * 512 + lane * 8] = r2;        \
    *(uint4*)&As[B][(rg1 * 2 + 1) * 512 + lane * 8] = r3;        \
    *(uint4*)&Bs[B][(wv  * 2 + 0) * 512 + lane * 8] = r4;        \
    *(uint4*)&Bs[B][(wv  * 2 + 1) * 512 + lane * 8] = r5;

#define COMPUTEB(B)                                                                            \
    {                                                                                          \
        bf16x8 af[4][2], bfr[2][2];                                                            \
        _Pragma("unroll")                                                                      \
        for (int i = 0; i < 4; ++i)                                                            \
            _Pragma("unroll")                                                                  \
            for (int kh = 0; kh < 2; ++kh)                                                     \
                af[i][kh] = *(const bf16x8*)&As[B][((wr * 4 + i) * 2 + kh) * 512 + lane * 8];   \
        _Pragma("unroll")                                                                      \
        for (int j = 0; j < 2; ++j)                                                            \
            _Pragma("unroll")                                                                  \
            for (int kh = 0; kh < 2; ++kh)                                                     \
                bfr[j][kh] = *(const bf16x8*)&Bs[B][((wc * 2 + j) * 2 + kh) * 512 + lane * 8]; \
        _Pragma("unroll")                                                                      \
        for (int kh = 0; kh < 2; ++kh)                                                         \
            _Pragma("unroll")                                                                  \
            for (int i = 0; i < 4; ++i)                                                        \
                _Pragma("unroll")                                                              \
                for (int j = 0; j < 2; ++j)                                                    \
                    acc[i][j] = __builtin_amdgcn_mfma_f32_16x16x32_bf16(af[i][kh], bfr[j][kh], \
                                                                        acc[i][j], 0, 0, 0);   \
    }

__global__ __launch_bounds__(256)
void gemm2_pipe(const unsigned short* __restrict__ A, const unsigned short* __restrict__ Bw,
                const float* __restrict__ bias, float* __restrict__ Cv)
{
    __shared__ __align__(16) unsigned short As[2][128 * 64];  // 2 x 16 KB
    __shared__ __align__(16) unsigned short Bs[2][64 * 64];   // 2 x 8 KB

    const int tid  = threadIdx.x;
    const int lane = tid & 63;
    const int wv   = tid >> 6;
    const int wr   = wv >> 1;
    const int wc   = wv & 1;
    const int id   = blockIdx.y * 16 + blockIdx.x;
    const int xcd  = id & 7;
    const int slot = id >> 3;
    const int by   = xcd * 4 + (slot >> 4);
    const int bx   = slot & 15;
    const int bm   = by * 128;
    const int bn   = bx * 64;
    const int m16  = lane & 15;
    const int kq   = lane >> 4;

    f32x4 acc[4][2] = {};

    const int rg0 = 2 * wv, rg1 = 2 * wv + 1;
    const unsigned short* gA0 = A  + (size_t)(bm + 16 * rg0 + m16) * En + kq * 8;
    const unsigned short* gA1 = A  + (size_t)(bm + 16 * rg1 + m16) * En + kq * 8;
    const unsigned short* gB0 = Bw + (size_t)(bn + 16 * wv  + m16) * En + kq * 8;

    uint4 p0, p1, p2, p3, p4, p5;
    uint4 q0, q1, q2, q3, q4, q5;

    LOAD6(0,  p0, p1, p2, p3, p4, p5);
    STORE6B(0, p0, p1, p2, p3, p4, p5);
    LOAD6(64, q0, q1, q2, q3, q4, q5);
    __syncthreads();

#pragma unroll 1
    for (int it = 0; it < 7; ++it) {
        const int kb = it * 128;
        LOAD6(kb + 128, p0, p1, p2, p3, p4, p5);
        COMPUTEB(0);
        STORE6B(1, q0, q1, q2, q3, q4, q5);
        __syncthreads();
        LOAD6(kb + 192, q0, q1, q2, q3, q4, q5);
        COMPUTEB(1);
        STORE6B(0, p0, p1, p2, p3, p4, p5);
        __syncthreads();
    }
    COMPUTEB(0);
    STORE6B(1, q0, q1, q2, q3, q4, q5);
    __syncthreads();
    COMPUTEB(1);

#pragma unroll
    for (int i = 0; i < 4; ++i) {
        const int r0_ = bm + wr * 64 + i * 16 + kq * 4;
#pragma unroll
        for (int j = 0; j < 2; ++j) {
            const int c0 = bn + wc * 32 + j * 16 + m16;
            const float bcol = bias[c0];
#pragma unroll
            for (int r = 0; r < 4; ++r)
                Cv[(size_t)(r0_ + r) * En + c0] = acc[i][j][r] + bcol;
        }
    }
}

// ---------------------------------------------------------------------------
// combine (R14): dual bf16 LDS tiles (vm0, vm1 staged with b128 — no VALU
// in staging, unlike R11's scalar fp32 writes), dual inline csum scan
// (scan cost proven ~0, R13), add at consumption. Wo cast slice kept.
//   out_pre[b,i,e] = (w2*Pref[i&~1] + (i odd)*w1*vm[i-1] + w0*(T-Pref[i]))/Z
//   Z = (i&~1)*w2 + (i odd)*w1 + (S-i)*w0 + 1e-8
// Grid (4, 64, 2) = 512 blocks; LDS 32 KB -> 2 blocks/CU.
// ---------------------------------------------------------------------------
__global__ __launch_bounds__(256)
void combine(const unsigned short* __restrict__ vm0, const unsigned short* __restrict__ vm1,
             const float* __restrict__ csum0, const float* __restrict__ csum1,
             const float* __restrict__ hier, const float* __restrict__ Wo,
             unsigned short* __restrict__ Wob, unsigned short* __restrict__ opre)
{
    __shared__ __align__(16) unsigned short tile0[CHUNK * 256];  // 16 KB
    __shared__ __align__(16) unsigned short tile1[CHUNK * 256];  // 16 KB

    const int tid = threadIdx.x;
    const int ec0 = blockIdx.x * 256;
    const int c   = blockIdx.y;     // chunk within batch, 0..63
    const int b   = blockIdx.z;

    // --- Stage both 32x256 vm tiles -> LDS (b128, 4 passes x 8 rows each).
    {
        const int lane16 = tid & 31;
        const int rbase  = tid >> 5;
        const size_t g0 = ((size_t)b * Sn + c * CHUNK) * En + ec0 + lane16 * 8;
#pragma unroll
        for (int r4 = 0; r4 < 4; ++r4) {
            const int row = r4 * 8 + rbase;
            *(uint4*)&tile0[row * 256 + lane16 * 8] =
                *(const uint4*)(vm0 + g0 + (size_t)row * En);
            *(uint4*)&tile1[row * 256 + lane16 * 8] =
                *(const uint4*)(vm1 + g0 + (size_t)row * En);
        }
    }

    // --- Wo cast slice: 512 blocks x 256 threads x 8 elems = 1M elements.
    {
        const int fid = (blockIdx.z * 64 + blockIdx.y) * 4 + blockIdx.x;  // 0..511
        const int base = fid * 2048 + tid * 4;
#pragma unroll
        for (int half = 0; half < 2; ++half) {
            const int off = base + half * 1024;
            const float4 v = *(const float4*)(Wo + off);
            ushort4 o;
            o.x = f2bf(v.x); o.y = f2bf(v.y); o.z = f2bf(v.z); o.w = f2bf(v.w);
            *(ushort4*)(Wob + off) = o;
        }
    }

    const int e = ec0 + tid;
    const int h = e >> 6;   // dh = 64
    const float w0 = hier[((size_t)b * Hn + h) * 3 + 0];
    const float w1 = hier[((size_t)b * Hn + h) * 3 + 1] * 0.5f;
    const float w2 = hier[((size_t)b * Hn + h) * 3 + 2] * 0.25f;

    // --- Dual exclusive scan over csum0+csum1 (hidden under staging, R13).
    float run = 0.0f, T = 0.0f;
    {
        const float* cp0 = csum0 + (size_t)b * NCH * En + e;
        const float* cp1 = csum1 + (size_t)b * NCH * En + e;
#pragma unroll 16
        for (int c2 = 0; c2 < NCH; ++c2) {
            const float v = cp0[(size_t)c2 * En] + cp1[(size_t)c2 * En];
            T += v;
            run += (c2 < c) ? v : 0.0f;
        }
    }

    __syncthreads();   // vm tiles visible

    float prev = 0.0f;
    const size_t base = ((size_t)b * Sn + c * CHUNK) * En + e;

#pragma unroll
    for (int t = 0; t < CHUNK; ++t) {
        const int i = c * CHUNK + t;
        const float cur = bf2f(tile0[t * 256 + tid]) + bf2f(tile1[t * 256 + tid]);
        float num, Z;
        if (i & 1) {
            num = w2 * (run - prev) + w1 * prev + w0 * (T - run);
            Z = (float)(i - 1) * w2 + w1 + (float)(Sn - i) * w0 + 1e-8f;
        } else {
            num = w2 * run + w0 * (T - run);
            Z = (float)i * w2 + (float)(Sn - i) * w0 + 1e-8f;
        }
        opre[base + (size_t)t * En] = f2bf(num / Z);
        run += cur;
        prev = cur;
    }
}

// ---------------------------------------------------------------------------
extern "C" void kernel_launch(void* const* d_in, const int* in_sizes, int n_in,
                              void* d_out, int out_size, void* d_ws, size_t ws_size,
                              hipStream_t stream)
{
    // 0:x 1:attention_mask 2:level_indices 3:Wq 4:bq 5:Wk 6:bk 7:Wv 8:bv 9:hier 10:Wo 11:bo
    const float* x    = (const float*)d_in[0];
    const int*   mask = (const int*)d_in[1];
    const float* Wv   = (const float*)d_in[7];
    const float* bv   = (const float*)d_in[8];
    const float* hier = (const float*)d_in[9];
    const float* Wo   = (const float*)d_in[10];
    const float* bo   = (const float*)d_in[11];
    float* out = (float*)d_out;

    char* ws = (char*)d_ws;
    unsigned short* xb    = (unsigned short*)ws;  ws += (size_t)Mtot * En * 2;   // 8 MB
    unsigned short* Wvb   = (unsigned short*)ws;  ws += (size_t)En * En * 2;     // 2 MB
    unsigned short* Wob   = (unsigned short*)ws;  ws += (size_t)En * En * 2;     // 2 MB
    unsigned short* vmb0  = (unsigned short*)ws;  ws += (size_t)Mtot * En * 2;   // 8 MB
    unsigned short* vmb1  = (unsigned short*)ws;  ws += (size_t)Mtot * En * 2;   // 8 MB
    float*          csum0 = (float*)ws;           ws += (size_t)GCH * En * 4;    // 512 KB
    float*          csum1 = (float*)ws;           ws += (size_t)GCH * En * 4;    // 512 KB
    unsigned short* opreb = (unsigned short*)ws;  ws += (size_t)Mtot * En * 2;   // 8 MB

    dim3 threads(256);

    // Casts to bf16: x + Wv only (Wo is cast inside combine, pre-gemm2)
    cast2<<<dim3((XN + WN) / 1024), threads, 0, stream>>>(x, Wv, xb, Wvb);

    // 1) split-K=2 on 128x128 tiles: traffic 192->128 MB at 2 blocks/CU.
    gemm1_sk128<<<dim3(8, 32, 2), threads, 0, stream>>>(xb, Wvb, bv, mask,
                                                        vmb0, vmb1, csum0, csum1);
    // 2) Wo cast + dual-tile staging + dual scan + combine -> opre (bf16)
    combine<<<dim3(En / 256, NCH, Bn), threads, 0, stream>>>(vmb0, vmb1, csum0, csum1,
                                                             hier, Wo, Wob, opreb);
    // 3) out = opre @ Wo.T + bo (fp32 out) — R8 config unchanged
    gemm2_pipe<<<dim3(16, 32), threads, 0, stream>>>(opreb, Wob, bo, out);
}